// Round 22
// baseline (340.315 us; speedup 1.0000x reference)
//
#include <hip/hip_runtime.h>
#include <cstdint>
#include <cstddef>

typedef __attribute__((ext_vector_type(4))) float f32x4;
typedef __attribute__((ext_vector_type(8))) short bf16x8;

#define S_LEN 2048
#define HDIM 4096
#define QKVD 6144
#define NHEAD 32
#define NKVH 8
#define HD 128
// Q pre-scaled by ATT_SCALE * log2(e): softmax runs in exp2 domain
#define QPRE 0.12751744631123533f

// fp32 -> bf16 RNE (finite inputs only)
__device__ __forceinline__ short f2bf(float f) {
  unsigned int u = __float_as_uint(f);
  u += 0x7FFFu + ((u >> 16) & 1u);
  return (short)(u >> 16);
}
__device__ __forceinline__ float bf2f(short s) {
  return __uint_as_float((unsigned int)(unsigned short)s << 16);
}

// async global->LDS, 16B per lane. LDS dest = wave-uniform base + lane*16.
__device__ __forceinline__ void gl_lds16(const short* g, short* l) {
  __builtin_amdgcn_global_load_lds((const __attribute__((address_space(1))) void*)g,
                                   (__attribute__((address_space(3))) void*)l,
                                   16, 0, 0);
}

template<int N> __device__ __forceinline__ void vmw() {
  if constexpr (N == 0) asm volatile("s_waitcnt vmcnt(0)" ::: "memory");
  else if constexpr (N == 1) asm volatile("s_waitcnt vmcnt(1)" ::: "memory");
  else if constexpr (N == 2) asm volatile("s_waitcnt vmcnt(2)" ::: "memory");
  else if constexpr (N == 3) asm volatile("s_waitcnt vmcnt(3)" ::: "memory");
  else if constexpr (N == 4) asm volatile("s_waitcnt vmcnt(4)" ::: "memory");
  // N==99: no wait
}

// fused fp32->bf16 conversion over up to two buffers (one launch)
__global__ void cvt2_kernel(const float* __restrict__ a, short* __restrict__ oa, int na,
                            const float* __restrict__ b, short* __restrict__ ob, int nb) {
  int i = (blockIdx.x * blockDim.x + threadIdx.x) * 4;
  const float* src; short* dst;
  if (i < na) { src = a + i; dst = oa + i; }
  else if (i < na + nb) { src = b + (i - na); dst = ob + (i - na); }
  else return;
  const float4 v = *reinterpret_cast<const float4*>(src);
  short4 o;
  o.x = f2bf(v.x); o.y = f2bf(v.y); o.z = f2bf(v.z); o.w = f2bf(v.w);
  *reinterpret_cast<short4*>(dst) = o;
}

// ---------------------------------------------------------------------------
// 4-phase snake GEMM with register-held frags (round-13/19/21 verified:
// ~97.5us, MfmaUtil ~45%, 0 bank conflicts). Gates (2, NQ+1, none, NQ+1) are
// the MINIMAL CORRECT ledger (round-20 refutation: each phase's gate protects
// the NEXT phase's reads). Round-14 lesson: keep 4 fine phases.
// ---------------------------------------------------------------------------
#define PHASE(MH, NH, LOADA, LOADB, VM, STAGE) { \
    if (LOADA) { const short* bA = lA + buf * ATILE; \
      _Pragma("unroll") for (int m = 0; m < 2; ++m) { \
        int row = wm * 64 + (MH) * 32 + m * 16 + l15; \
        _Pragma("unroll") for (int kk = 0; kk < 2; ++kk) { \
          int slot = ((kk << 2) + l4) ^ (row & 7); \
          afH[m][kk] = *reinterpret_cast<const bf16x8*>(bA + row * 64 + slot * 8); } } } \
    if (LOADB) { const short* bB = lB + buf * BTILE; \
      _Pragma("unroll") for (int n = 0; n < NQ; ++n) { \
        int row = wn * (BN >> 2) + n * 32 + (NH) * 16 + l15; \
        _Pragma("unroll") for (int kk = 0; kk < 2; ++kk) { \
          int slot = ((kk << 2) + l4) ^ (row & 7); \
          bfH[n][kk] = *reinterpret_cast<const bf16x8*>(bB + row * 64 + slot * 8); } } } \
    STAGE; \
    vmw<(VM)>(); \
    __builtin_amdgcn_s_barrier(); \
    __builtin_amdgcn_sched_barrier(0); \
    __builtin_amdgcn_s_setprio(1); \
    _Pragma("unroll") for (int m = 0; m < 2; ++m) \
      _Pragma("unroll") for (int n = 0; n < NQ; ++n) \
        _Pragma("unroll") for (int kk = 0; kk < 2; ++kk) \
          acc[(MH) * 2 + m][(NH) * NQ + n] = __builtin_amdgcn_mfma_f32_16x16x32_bf16( \
              afH[m][kk], bfH[n][kk], acc[(MH) * 2 + m][(NH) * NQ + n], 0, 0, 0); \
    __builtin_amdgcn_s_setprio(0); }

template<int BN>
__global__ __launch_bounds__(512, 2) void gemm8p(const short* __restrict__ A,
                                                 const short* __restrict__ B,
                                                 float* __restrict__ C,
                                                 int M, int N, int K) {
  extern __shared__ short sm[];
  constexpr int NQ = BN / 128;
  constexpr int ATILE = 128 * 64;
  constexpr int BTILE = BN * 64;
  const int tid = threadIdx.x;
  const int wv = tid >> 6, lane = tid & 63;
  const int wm = wv >> 2, wn = wv & 3;
  const int l15 = lane & 15, l4 = lane >> 4;
  const int nbn = N / BN;
  const int nwg = gridDim.x;
  const int bid = blockIdx.x;
  const int sbid = (bid & 7) * (nwg >> 3) + (bid >> 3);  // XCD-contiguous (nwg%8==0)
  const int tm = (sbid / nbn) * 128, tn = (sbid % nbn) * BN;
  short* lA = sm;
  short* lB = sm + 2 * ATILE;
  (void)M;

  f32x4 acc[4][2 * NQ] = {};
  bf16x8 afH[2][2], bfH[NQ][2];

  auto stageA = [&](int k0, int bufi, int sel) {
    short* dst = lA + bufi * ATILE;
    int rowIdx = tid >> 3;
    int row = (rowIdx >> 5) * 64 + sel * 32 + (rowIdx & 31);
    int slot = tid & 7;
    gl_lds16(A + (size_t)(tm + row) * K + k0 + ((slot ^ (row & 7)) << 3),
             dst + row * 64 + slot * 8);
  };
  auto stageB = [&](int k0, int bufi, int par) {
    short* dst = lB + bufi * BTILE;
#pragma unroll
    for (int j = 0; j < NQ; ++j) {
      int rowIdx = (tid >> 3) + j * 64;
      int row = (rowIdx >> 4) * 32 + par * 16 + (rowIdx & 15);
      int slot = tid & 7;
      gl_lds16(B + (size_t)(tn + row) * K + k0 + ((slot ^ (row & 7)) << 3),
               dst + row * 64 + slot * 8);
    }
  };

  // prologue: tile 0, issue order = consume order
  stageA(0, 0, 0);
  stageB(0, 0, 0);
  stageB(0, 0, 1);
  stageA(0, 0, 1);
  vmw<NQ + 1>();
  __builtin_amdgcn_s_barrier();
  __builtin_amdgcn_sched_barrier(0);

  const int KT = K >> 6;
  for (int t = 0; t < KT - 1; ++t) {
    const int buf = t & 1, nbuf = buf ^ 1, nk0 = (t + 1) << 6;
    PHASE(0, 0, 1, 1, 2,      stageA(nk0, nbuf, 0))
    PHASE(0, 1, 0, 1, NQ + 1, stageB(nk0, nbuf, 0))
    PHASE(1, 1, 1, 0, 99,     stageB(nk0, nbuf, 1))
    PHASE(1, 0, 0, 1, NQ + 1, stageA(nk0, nbuf, 1))
  }
  {  // tail tile: no staging; drain progressively
    const int buf = (KT - 1) & 1;
    PHASE(0, 0, 1, 1, 1,  (void)0)
    PHASE(0, 1, 0, 1, 0,  (void)0)
    PHASE(1, 1, 1, 0, 99, (void)0)
    PHASE(1, 0, 0, 1, 99, (void)0)
  }
#pragma unroll
  for (int mg = 0; mg < 4; ++mg)
#pragma unroll
    for (int NH = 0; NH < 2; ++NH)
#pragma unroll
      for (int n = 0; n < NQ; ++n)
#pragma unroll
        for (int r = 0; r < 4; ++r) {
          int row = tm + wm * 64 + mg * 16 + l4 * 4 + r;
          int col = tn + wn * (BN >> 2) + n * 32 + NH * 16 + l15;
          C[(size_t)row * N + col] = acc[mg][NH * NQ + n][r];
        }
}

// fused mid kernel: rope (blocks [0,20480)) + V-transpose (blocks [20480,20992)).
__global__ __launch_bounds__(256) void midk_kernel(const float* __restrict__ qkv,
                                                   const float* __restrict__ cb,
                                                   const float* __restrict__ sb,
                                                   short* __restrict__ Q,
                                                   short* __restrict__ Kx,
                                                   short* __restrict__ Vt) {
  __shared__ short tile[64][72];
  if (blockIdx.x < 20480) {
    int tid = blockIdx.x * 256 + threadIdx.x;
    int dh = tid & 63;
    int t2 = tid >> 6;
    int part = t2 % 5;
    int t3 = t2 / 5;
    int g = t3 & 7;
    int s = t3 >> 3;
    const float* base = qkv + (size_t)s * QKVD + g * 768 + part * 128;
    float v1 = base[dh], v2 = base[dh + 64];
    float c = cb[s * HD + dh], sn = sb[s * HD + dh];
    float o1 = v1 * c - v2 * sn;
    float o2 = v2 * c + v1 * sn;
    if (part < 4) {
      o1 *= QPRE; o2 *= QPRE;
      short* dst = Q + ((size_t)(g * 4 + part) * S_LEN + s) * HD;
      dst[dh] = f2bf(o1);
      dst[dh + 64] = f2bf(o2);
    } else {
      short* dst = Kx + ((size_t)g * S_LEN + s) * HD;
      dst[dh] = f2bf(o1);
      dst[dh + 64] = f2bf(o2);
    }
  } else {
    const int b = blockIdx.x - 20480;
    const int kvh = b >> 6;
    const int s0 = ((b & 63) >> 1) * 64, d0 = (b & 1) * 64;
    const int t = threadIdx.x;
#pragma unroll
    for (int i = 0; i < 4; ++i) {
      int c = t + i * 256;
      int sl = c >> 4, dl = (c & 15) * 4;
      const float4 v = *reinterpret_cast<const float4*>(
          qkv + (size_t)(s0 + sl) * QKVD + kvh * 768 + 640 + d0 + dl);
      tile[sl][dl] = f2bf(v.x); tile[sl][dl + 1] = f2bf(v.y);
      tile[sl][dl + 2] = f2bf(v.z); tile[sl][dl + 3] = f2bf(v.w);
    }
    __syncthreads();
    short* Vtb = Vt + (size_t)kvh * HD * S_LEN;
#pragma unroll
    for (int i = 0; i < 2; ++i) {
      int dl = i * 32 + (t >> 3), sl = (t & 7) * 8;
      bf16x8 o;
#pragma unroll
      for (int j = 0; j < 8; ++j) o[j] = tile[sl + j][dl];
      *reinterpret_cast<bf16x8*>(Vtb + (size_t)(d0 + dl) * S_LEN + s0 + sl) = o;
    }
  }
}

// flash attention v9: 3-way kv-split + defer-max, (256,2).
// Split z handles tiles [(nkt*z)/3, (nkt*(z+1))/3); max block work drops
// 17 -> 11 tiles (tail balance). Empty splits write m=-1e30, l=0 partials
// which contribute exactly zero in the combine.
__global__ __launch_bounds__(256, 2) void attn_kernel(const short* __restrict__ Q,
                                                      const short* __restrict__ Kx,
                                                      const short* __restrict__ Vt,
                                                      short* __restrict__ Pt,
                                                      float2* __restrict__ St) {
  __shared__ short lK[2 * 64 * 128];
  __shared__ unsigned int lPu[4 * 2 * 512];
  const int tt = threadIdx.x;
  const int w = tt >> 6, lane = tt & 63;
  const int l15 = lane & 15, l4 = lane >> 4;
  const int kvh = blockIdx.x;
  const int qt = 63 - blockIdx.y;
  const int z = blockIdx.z;
  const int h = kvh * 4 + w;
  short* pout = Pt + (size_t)z * ((size_t)NHEAD * S_LEN * HD);
  float2* sout = St + (size_t)z * (NHEAD * S_LEN);

  const int nkt = (qt >> 1) + 1;
  const int t0 = (nkt * z) / 3;
  const int t1 = (nkt * (z + 1)) / 3;

  f32x4 o[2][8] = {};
  float m_run[2] = {-1e30f, -1e30f};
  float lsum[2] = {0.f, 0.f};

  if (t0 < t1) {
    const short* Kb = Kx + (size_t)kvh * S_LEN * HD;
    const short* Vb = Vt + (size_t)kvh * HD * S_LEN;

    {  // stage first K tile
      const short* Kg = Kb + (size_t)(t0 * 64) * HD;
#pragma unroll
      for (int i = 0; i < 4; ++i) {
        int c = tt + i * 256, row = c >> 4, jj = (c & 15) ^ (row & 7);
        gl_lds16(Kg + (size_t)row * HD + jj * 8, lK + c * 8);
      }
    }
    bf16x8 qf[2][4];
#pragma unroll
    for (int qa = 0; qa < 2; ++qa) {
      const short* qrow = Q + ((size_t)h * S_LEN + qt * 32 + qa * 16 + l15) * HD + l4 * 8;
#pragma unroll
      for (int fd = 0; fd < 4; ++fd)
        qf[qa][fd] = *reinterpret_cast<const bf16x8*>(qrow + fd * 32);
    }
    __syncthreads();

    int cur = 0;
    for (int kt = t0; kt < t1; ++kt) {
      const int c0 = kt * 64;
      if (kt + 1 < t1) {
        const short* Kg = Kb + (size_t)(c0 + 64) * HD;
        short* dst = lK + (cur ^ 1) * (64 * 128);
#pragma unroll
        for (int i = 0; i < 4; ++i) {
          int c = tt + i * 256, row = c >> 4, jj = (c & 15) ^ (row & 7);
          gl_lds16(Kg + (size_t)row * HD + jj * 8, dst + c * 8);
        }
      }
      const short* src = lK + cur * (64 * 128);
      f32x4 sf[2][4] = {};
      __builtin_amdgcn_s_setprio(1);
#pragma unroll
      for (int n = 0; n < 4; ++n) {
        bf16x8 kf[4];
#pragma unroll
        for (int fd = 0; fd < 4; ++fd) {
          int row = n * 16 + l15, jp = (l4 + fd * 4) ^ (l15 & 7);
          kf[fd] = *reinterpret_cast<const bf16x8*>(src + row * 128 + jp * 8);
        }
#pragma unroll
        for (int fd = 0; fd < 4; ++fd) {
          sf[0][n] = __builtin_amdgcn_mfma_f32_16x16x32_bf16(kf[fd], qf[0][fd], sf[0][n], 0, 0, 0);
          sf[1][n] = __builtin_amdgcn_mfma_f32_16x16x32_bf16(kf[fd], qf[1][fd], sf[1][n], 0, 0, 0);
        }
      }
      __builtin_amdgcn_s_setprio(0);
      bf16x8 vreg[8][2];
#pragma unroll
      for (int fd = 0; fd < 8; ++fd) {
        const short* vrow = Vb + (size_t)(fd * 16 + l15) * S_LEN + c0 + l4 * 8;
        vreg[fd][0] = *reinterpret_cast<const bf16x8*>(vrow);
        vreg[fd][1] = *reinterpret_cast<const bf16x8*>(vrow + 32);
      }
      const bool lastt = (kt == nkt - 1);
#pragma unroll
      for (int qa = 0; qa < 2; ++qa) {
        if (lastt) {  // wave-uniform: only the diagonal tile pays for masking
          const int qrow_g = qt * 32 + qa * 16 + l15;
#pragma unroll
          for (int n = 0; n < 4; ++n)
#pragma unroll
            for (int r = 0; r < 4; ++r)
              if ((c0 + n * 16 + l4 * 4 + r) > qrow_g) sf[qa][n][r] = -1e30f;
        }
        float mx = sf[qa][0][0];
#pragma unroll
        for (int n = 0; n < 4; ++n)
#pragma unroll
          for (int r = 0; r < 4; ++r) mx = fmaxf(mx, sf[qa][n][r]);
        mx = fmaxf(mx, __shfl_xor(mx, 16, 64));
        mx = fmaxf(mx, __shfl_xor(mx, 32, 64));
        // defer-max (T13): skip alpha shuffles + O-rescale when max stable.
        float mnew;
        if (__all(mx <= m_run[qa] + 8.f)) {
          mnew = m_run[qa];
        } else {
          mnew = fmaxf(m_run[qa], mx);
          float alpha = exp2f(m_run[qa] - mnew);
          m_run[qa] = mnew;
          lsum[qa] *= alpha;
          float aO[4];
#pragma unroll
          for (int r = 0; r < 4; ++r) aO[r] = __shfl(alpha, l4 * 4 + r, 64);
#pragma unroll
          for (int fd = 0; fd < 8; ++fd) {
            o[qa][fd][0] *= aO[0]; o[qa][fd][1] *= aO[1];
            o[qa][fd][2] *= aO[2]; o[qa][fd][3] *= aO[3];
          }
        }
        float ps = 0.f;
#pragma unroll
        for (int n = 0; n < 4; ++n)
#pragma unroll
          for (int r = 0; r < 4; ++r) {
            float e = exp2f(sf[qa][n][r] - mnew);
            sf[qa][n][r] = e;
            ps += e;
          }
        lsum[qa] += ps;
#pragma unroll
        for (int n = 0; n < 4; ++n)
#pragma unroll
          for (int rp = 0; rp < 2; ++rp) {
            unsigned int pkv =
                ((unsigned int)(unsigned short)f2bf(sf[qa][n][rp * 2 + 1]) << 16) |
                (unsigned short)f2bf(sf[qa][n][rp * 2]);
            int kv5 = ((n & 1) << 4) + l4 * 4 + rp * 2;
            lPu[w * 1024 + qa * 512 + ((n >> 1) << 8) +
                (l15 + ((kv5 >> 3) << 4)) * 4 + ((kv5 & 7) >> 1)] = pkv;
          }
      }
      asm volatile("s_waitcnt lgkmcnt(0)" ::: "memory");
      bf16x8 pf[2][2];
#pragma unroll
      for (int qa = 0; qa < 2; ++qa)
#pragma unroll
        for (int p = 0; p < 2; ++p)
          pf[qa][p] = *reinterpret_cast<const bf16x8*>(
              (const short*)lPu + (w * 1024 + qa * 512 + p * 256 + lane * 4) * 2);
      __builtin_amdgcn_s_setprio(1);
#pragma unroll
      for (int fd = 0; fd < 8; ++fd) {
        o[0][fd] = __builtin_amdgcn_mfma_f32_16x16x32_bf16(pf[0][0], vreg[fd][0], o[0][fd], 0, 0, 0);
        o[0][fd] = __builtin_amdgcn_mfma_f32_16x16x32_bf16(pf[0][1], vreg[fd][1], o[0][fd], 0, 0, 0);
        o[1][fd] = __builtin_amdgcn_mfma_f32_16x16x32_bf16(pf[1][0], vreg[fd][0], o[1][fd], 0, 0, 0);
        o[1][fd] = __builtin_amdgcn_mfma_f32_16x16x32_bf16(pf[1][1], vreg[fd][1], o[1][fd], 0, 0, 0);
      }
      __builtin_amdgcn_s_setprio(0);
      __syncthreads();
      cur ^= 1;
    }
  }
  // epilogue: reduce lsum, write stats + unnormalized partial O
#pragma unroll
  for (int qa = 0; qa < 2; ++qa) {
    float s = lsum[qa];
    s += __shfl_xor(s, 16, 64);
    s += __shfl_xor(s, 32, 64);
    if (l4 == 0)
      sout[(size_t)h * S_LEN + qt * 32 + qa * 16 + l15] = make_float2(m_run[qa], s);
#pragma unroll
    for (int fd = 0; fd < 8; ++fd)
#pragma unroll
      for (int r = 0; r < 4; ++r)
        pout[((size_t)h * S_LEN + qt * 32 + qa * 16 + l4 * 4 + r) * HD + fd * 16 + l15] =
            f2bf(o[qa][fd][r]);
  }
}

// merge the three kv-split partials -> AO, plus the w_proj fp32->bf16 pass
__global__ __launch_bounds__(256) void combine3_kernel(const short* __restrict__ Pt,
                                                       const float2* __restrict__ St,
                                                       short* __restrict__ AO,
                                                       const float* __restrict__ wpf,
                                                       short* __restrict__ wpb) {
  {
    size_t base = (size_t)blockIdx.x * 4096 + threadIdx.x * 4;
#pragma unroll
    for (int it = 0; it < 4; ++it) {
      const float4 v = *reinterpret_cast<const float4*>(wpf + base + it * 1024);
      short4 oo;
      oo.x = f2bf(v.x); oo.y = f2bf(v.y); oo.z = f2bf(v.z); oo.w = f2bf(v.w);
      *reinterpret_cast<short4*>(wpb + base + it * 1024) = oo;
    }
  }
  const size_t PSZ = (size_t)NHEAD * S_LEN * HD;  // 8388608
  const int NS = NHEAD * S_LEN;                   // 65536
  int idx = (blockIdx.x * 256 + threadIdx.x) * 8;  // over NH*S*HD
  int h = idx >> 18;                 // S*HD = 2^18
  int rem = idx & ((1 << 18) - 1);
  int s = rem >> 7, d = rem & 127;
  int hs = h * S_LEN + s;
  float2 a = St[hs];
  float2 b = St[NS + hs];
  float2 c = St[2 * NS + hs];
  float M = fmaxf(fmaxf(a.x, b.x), c.x);
  float w0 = exp2f(a.x - M), w1 = exp2f(b.x - M), w2 = exp2f(c.x - M);
  float inv = 1.f / (a.y * w0 + b.y * w1 + c.y * w2);
  w0 *= inv; w1 *= inv; w2 *= inv;
  bf16x8 v0 = *reinterpret_cast<const bf16x8*>(Pt + idx);
  bf16x8 v1 = *reinterpret_cast<const bf16x8*>(Pt + PSZ + idx);
  bf16x8 v2 = *reinterpret_cast<const bf16x8*>(Pt + 2 * PSZ + idx);
  bf16x8 ov;
#pragma unroll
  for (int j = 0; j < 8; ++j)
    ov[j] = f2bf(bf2f(v0[j]) * w0 + bf2f(v1[j]) * w1 + bf2f(v2[j]) * w2);
  *reinterpret_cast<bf16x8*>(AO + (size_t)s * HDIM + h * HD + d) = ov;
}

extern "C" void kernel_launch(void* const* d_in, const int* in_sizes, int n_in,
                              void* d_out, int out_size, void* d_ws, size_t ws_size,
                              hipStream_t stream) {
  const float* hidden = (const float*)d_in[0];
  const float* w_attn = (const float*)d_in[1];
  const float* w_proj = (const float*)d_in[2];
  const float* rcos = (const float*)d_in[3];
  const float* rsin = (const float*)d_in[4];
  float* out = (float*)d_out;
  char* ws = (char*)d_ws;

  // workspace layout v2 (overlaid, 112 MiB), liveness checked per kernel:
  //  [0,16Mi)    Xb (bf16 X; dead after gemm1) -> AO (written by combine3)
  //  [16,64Mi)   Wab (dead after gemm1) -> Qb[16,32) Kb[32,36) Vtb[36,40)
  //              (all dead after attn) -> Wpb[16,48) (written by combine3)
  //  [60,61.5Mi) St (3 x 512KiB stats; written by attn, read by combine3)
  //  [64,112Mi)  QKVf (fp32; dead after midk) -> Pt[64,112) (3 x 16Mi partials)
  short* Xb  = (short*)(ws);
  short* Wab = (short*)(ws + (16u << 20));
  short* Qb  = (short*)(ws + (16u << 20));
  short* Kb  = (short*)(ws + (32u << 20));
  short* Vtb = (short*)(ws + (36u << 20));
  short* Wpb = (short*)(ws + (16u << 20));   // written by combine3 (Q/K/Vt dead)
  float2* St = (float2*)(ws + (60u << 20));
  float* QKVf = (float*)(ws + (64u << 20));
  short* Pt  = (short*)(ws + (64u << 20));   // written after QKVf is dead
  short* AO  = Xb;

  const int nX = S_LEN * HDIM;       // 8388608
  const int nWa = QKVD * HDIM;       // 25165824

  hipFuncSetAttribute(reinterpret_cast<const void*>(gemm8p<384>),
                      hipFuncAttributeMaxDynamicSharedMemorySize, 131072);
  hipFuncSetAttribute(reinterpret_cast<const void*>(gemm8p<256>),
                      hipFuncAttributeMaxDynamicSharedMemorySize, 98304);

  cvt2_kernel<<<(nX + nWa) / 1024, 256, 0, stream>>>(hidden, Xb, nX, w_attn, Wab, nWa);
  gemm8p<384><<<256, 512, 131072, stream>>>(Xb, Wab, QKVf, S_LEN, QKVD, HDIM);
  midk_kernel<<<20992, 256, 0, stream>>>(QKVf, rcos, rsin, Qb, Kb, Vtb);
  attn_kernel<<<dim3(NKVH, 64, 3), 256, 0, stream>>>(Qb, Kb, Vtb, Pt, St);
  combine3_kernel<<<(NHEAD * S_LEN * HD / 8) / 256, 256, 0, stream>>>(
      Pt, St, AO, w_proj, Wpb);
  gemm8p<256><<<256, 512, 98304, stream>>>(AO, Wpb, out, S_LEN, HDIM, HDIM);
}

// Round 23
// 324.470 us; speedup vs baseline: 1.0488x; 1.0488x over previous
//
#include <hip/hip_runtime.h>
#include <cstdint>
#include <cstddef>

typedef __attribute__((ext_vector_type(4))) float f32x4;
typedef __attribute__((ext_vector_type(8))) short bf16x8;

#define S_LEN 2048
#define HDIM 4096
#define QKVD 6144
#define NHEAD 32
#define NKVH 8
#define HD 128
// Q pre-scaled by ATT_SCALE * log2(e): softmax runs in exp2 domain
#define QPRE 0.12751744631123533f

// fp32 -> bf16 RNE (finite inputs only)
__device__ __forceinline__ short f2bf(float f) {
  unsigned int u = __float_as_uint(f);
  u += 0x7FFFu + ((u >> 16) & 1u);
  return (short)(u >> 16);
}
__device__ __forceinline__ float bf2f(short s) {
  return __uint_as_float((unsigned int)(unsigned short)s << 16);
}

// async global->LDS, 16B per lane. LDS dest = wave-uniform base + lane*16.
__device__ __forceinline__ void gl_lds16(const short* g, short* l) {
  __builtin_amdgcn_global_load_lds((const __attribute__((address_space(1))) void*)g,
                                   (__attribute__((address_space(3))) void*)l,
                                   16, 0, 0);
}

template<int N> __device__ __forceinline__ void vmw() {
  if constexpr (N == 0) asm volatile("s_waitcnt vmcnt(0)" ::: "memory");
  else if constexpr (N == 1) asm volatile("s_waitcnt vmcnt(1)" ::: "memory");
  else if constexpr (N == 2) asm volatile("s_waitcnt vmcnt(2)" ::: "memory");
  else if constexpr (N == 3) asm volatile("s_waitcnt vmcnt(3)" ::: "memory");
  else if constexpr (N == 4) asm volatile("s_waitcnt vmcnt(4)" ::: "memory");
  // N==99: no wait
}

// fused fp32->bf16 conversion over up to two buffers (one launch)
__global__ void cvt2_kernel(const float* __restrict__ a, short* __restrict__ oa, int na,
                            const float* __restrict__ b, short* __restrict__ ob, int nb) {
  int i = (blockIdx.x * blockDim.x + threadIdx.x) * 4;
  const float* src; short* dst;
  if (i < na) { src = a + i; dst = oa + i; }
  else if (i < na + nb) { src = b + (i - na); dst = ob + (i - na); }
  else return;
  const float4 v = *reinterpret_cast<const float4*>(src);
  short4 o;
  o.x = f2bf(v.x); o.y = f2bf(v.y); o.z = f2bf(v.z); o.w = f2bf(v.w);
  *reinterpret_cast<short4*>(dst) = o;
}

// ---------------------------------------------------------------------------
// 4-phase snake GEMM with register-held frags (round-13/19/21 verified:
// ~97.5us, MfmaUtil ~45%, 0 bank conflicts). Gates (2, NQ+1, none, NQ+1) are
// the MINIMAL CORRECT ledger (round-20 refutation: each phase's gate protects
// the NEXT phase's reads). Round-14 lesson: keep 4 fine phases.
// Refuted directions ledger: 2-phase merge (r14), gate removal (r20),
// w_proj-in-attn (r15/17), occupancy-3 (r16), 3-way kv-split (r22).
// ---------------------------------------------------------------------------
#define PHASE(MH, NH, LOADA, LOADB, VM, STAGE) { \
    if (LOADA) { const short* bA = lA + buf * ATILE; \
      _Pragma("unroll") for (int m = 0; m < 2; ++m) { \
        int row = wm * 64 + (MH) * 32 + m * 16 + l15; \
        _Pragma("unroll") for (int kk = 0; kk < 2; ++kk) { \
          int slot = ((kk << 2) + l4) ^ (row & 7); \
          afH[m][kk] = *reinterpret_cast<const bf16x8*>(bA + row * 64 + slot * 8); } } } \
    if (LOADB) { const short* bB = lB + buf * BTILE; \
      _Pragma("unroll") for (int n = 0; n < NQ; ++n) { \
        int row = wn * (BN >> 2) + n * 32 + (NH) * 16 + l15; \
        _Pragma("unroll") for (int kk = 0; kk < 2; ++kk) { \
          int slot = ((kk << 2) + l4) ^ (row & 7); \
          bfH[n][kk] = *reinterpret_cast<const bf16x8*>(bB + row * 64 + slot * 8); } } } \
    STAGE; \
    vmw<(VM)>(); \
    __builtin_amdgcn_s_barrier(); \
    __builtin_amdgcn_sched_barrier(0); \
    __builtin_amdgcn_s_setprio(1); \
    _Pragma("unroll") for (int m = 0; m < 2; ++m) \
      _Pragma("unroll") for (int n = 0; n < NQ; ++n) \
        _Pragma("unroll") for (int kk = 0; kk < 2; ++kk) \
          acc[(MH) * 2 + m][(NH) * NQ + n] = __builtin_amdgcn_mfma_f32_16x16x32_bf16( \
              afH[m][kk], bfH[n][kk], acc[(MH) * 2 + m][(NH) * NQ + n], 0, 0, 0); \
    __builtin_amdgcn_s_setprio(0); }

template<int BN>
__global__ __launch_bounds__(512, 2) void gemm8p(const short* __restrict__ A,
                                                 const short* __restrict__ B,
                                                 float* __restrict__ C,
                                                 int M, int N, int K) {
  extern __shared__ short sm[];
  constexpr int NQ = BN / 128;
  constexpr int ATILE = 128 * 64;
  constexpr int BTILE = BN * 64;
  const int tid = threadIdx.x;
  const int wv = tid >> 6, lane = tid & 63;
  const int wm = wv >> 2, wn = wv & 3;
  const int l15 = lane & 15, l4 = lane >> 4;
  const int nbn = N / BN;
  const int nwg = gridDim.x;
  const int bid = blockIdx.x;
  const int sbid = (bid & 7) * (nwg >> 3) + (bid >> 3);  // XCD-contiguous (nwg%8==0)
  const int tm = (sbid / nbn) * 128, tn = (sbid % nbn) * BN;
  short* lA = sm;
  short* lB = sm + 2 * ATILE;
  (void)M;

  f32x4 acc[4][2 * NQ] = {};
  bf16x8 afH[2][2], bfH[NQ][2];

  auto stageA = [&](int k0, int bufi, int sel) {
    short* dst = lA + bufi * ATILE;
    int rowIdx = tid >> 3;
    int row = (rowIdx >> 5) * 64 + sel * 32 + (rowIdx & 31);
    int slot = tid & 7;
    gl_lds16(A + (size_t)(tm + row) * K + k0 + ((slot ^ (row & 7)) << 3),
             dst + row * 64 + slot * 8);
  };
  auto stageB = [&](int k0, int bufi, int par) {
    short* dst = lB + bufi * BTILE;
#pragma unroll
    for (int j = 0; j < NQ; ++j) {
      int rowIdx = (tid >> 3) + j * 64;
      int row = (rowIdx >> 4) * 32 + par * 16 + (rowIdx & 15);
      int slot = tid & 7;
      gl_lds16(B + (size_t)(tn + row) * K + k0 + ((slot ^ (row & 7)) << 3),
               dst + row * 64 + slot * 8);
    }
  };

  // prologue: tile 0, issue order = consume order
  stageA(0, 0, 0);
  stageB(0, 0, 0);
  stageB(0, 0, 1);
  stageA(0, 0, 1);
  vmw<NQ + 1>();
  __builtin_amdgcn_s_barrier();
  __builtin_amdgcn_sched_barrier(0);

  const int KT = K >> 6;
  for (int t = 0; t < KT - 1; ++t) {
    const int buf = t & 1, nbuf = buf ^ 1, nk0 = (t + 1) << 6;
    PHASE(0, 0, 1, 1, 2,      stageA(nk0, nbuf, 0))
    PHASE(0, 1, 0, 1, NQ + 1, stageB(nk0, nbuf, 0))
    PHASE(1, 1, 1, 0, 99,     stageB(nk0, nbuf, 1))
    PHASE(1, 0, 0, 1, NQ + 1, stageA(nk0, nbuf, 1))
  }
  {  // tail tile: no staging; drain progressively
    const int buf = (KT - 1) & 1;
    PHASE(0, 0, 1, 1, 1,  (void)0)
    PHASE(0, 1, 0, 1, 0,  (void)0)
    PHASE(1, 1, 1, 0, 99, (void)0)
    PHASE(1, 0, 0, 1, 99, (void)0)
  }
#pragma unroll
  for (int mg = 0; mg < 4; ++mg)
#pragma unroll
    for (int NH = 0; NH < 2; ++NH)
#pragma unroll
      for (int n = 0; n < NQ; ++n)
#pragma unroll
        for (int r = 0; r < 4; ++r) {
          int row = tm + wm * 64 + mg * 16 + l4 * 4 + r;
          int col = tn + wn * (BN >> 2) + n * 32 + NH * 16 + l15;
          C[(size_t)row * N + col] = acc[mg][NH * NQ + n][r];
        }
}

// fused mid kernel: rope (blocks [0,20480)) + V-transpose (blocks [20480,20992)).
__global__ __launch_bounds__(256) void midk_kernel(const float* __restrict__ qkv,
                                                   const float* __restrict__ cb,
                                                   const float* __restrict__ sb,
                                                   short* __restrict__ Q,
                                                   short* __restrict__ Kx,
                                                   short* __restrict__ Vt) {
  __shared__ short tile[64][72];
  if (blockIdx.x < 20480) {
    int tid = blockIdx.x * 256 + threadIdx.x;
    int dh = tid & 63;
    int t2 = tid >> 6;
    int part = t2 % 5;
    int t3 = t2 / 5;
    int g = t3 & 7;
    int s = t3 >> 3;
    const float* base = qkv + (size_t)s * QKVD + g * 768 + part * 128;
    float v1 = base[dh], v2 = base[dh + 64];
    float c = cb[s * HD + dh], sn = sb[s * HD + dh];
    float o1 = v1 * c - v2 * sn;
    float o2 = v2 * c + v1 * sn;
    if (part < 4) {
      o1 *= QPRE; o2 *= QPRE;
      short* dst = Q + ((size_t)(g * 4 + part) * S_LEN + s) * HD;
      dst[dh] = f2bf(o1);
      dst[dh + 64] = f2bf(o2);
    } else {
      short* dst = Kx + ((size_t)g * S_LEN + s) * HD;
      dst[dh] = f2bf(o1);
      dst[dh + 64] = f2bf(o2);
    }
  } else {
    const int b = blockIdx.x - 20480;
    const int kvh = b >> 6;
    const int s0 = ((b & 63) >> 1) * 64, d0 = (b & 1) * 64;
    const int t = threadIdx.x;
#pragma unroll
    for (int i = 0; i < 4; ++i) {
      int c = t + i * 256;
      int sl = c >> 4, dl = (c & 15) * 4;
      const float4 v = *reinterpret_cast<const float4*>(
          qkv + (size_t)(s0 + sl) * QKVD + kvh * 768 + 640 + d0 + dl);
      tile[sl][dl] = f2bf(v.x); tile[sl][dl + 1] = f2bf(v.y);
      tile[sl][dl + 2] = f2bf(v.z); tile[sl][dl + 3] = f2bf(v.w);
    }
    __syncthreads();
    short* Vtb = Vt + (size_t)kvh * HD * S_LEN;
#pragma unroll
    for (int i = 0; i < 2; ++i) {
      int dl = i * 32 + (t >> 3), sl = (t & 7) * 8;
      bf16x8 o;
#pragma unroll
      for (int j = 0; j < 8; ++j) o[j] = tile[sl + j][dl];
      *reinterpret_cast<bf16x8*>(Vtb + (size_t)(d0 + dl) * S_LEN + s0 + sl) = o;
    }
  }
}

// flash attention v8: 2-way kv-split + defer-max, (256,2) (verified best;
// r22 refuted 3-way split: z-major dispatch serializes splits into
// generations, no makespan gain, 1.5x fixed costs).
__global__ __launch_bounds__(256, 2) void attn_kernel(const short* __restrict__ Q,
                                                      const short* __restrict__ Kx,
                                                      const short* __restrict__ Vt,
                                                      short* __restrict__ part0,
                                                      short* __restrict__ part1,
                                                      float2* __restrict__ stat0,
                                                      float2* __restrict__ stat1) {
  __shared__ short lK[2 * 64 * 128];
  __shared__ unsigned int lPu[4 * 2 * 512];
  const int tt = threadIdx.x;
  const int w = tt >> 6, lane = tt & 63;
  const int l15 = lane & 15, l4 = lane >> 4;
  const int kvh = blockIdx.x;
  const int qt = 63 - blockIdx.y;
  const int z = blockIdx.z;
  const int h = kvh * 4 + w;
  short* pout = z ? part1 : part0;
  float2* sout = z ? stat1 : stat0;

  const int nkt = (qt >> 1) + 1;
  const int ts = (nkt + 1) >> 1;
  const int t0 = z ? ts : 0;
  const int t1 = z ? nkt : ts;

  f32x4 o[2][8] = {};
  float m_run[2] = {-1e30f, -1e30f};
  float lsum[2] = {0.f, 0.f};

  if (t0 < t1) {
    const short* Kb = Kx + (size_t)kvh * S_LEN * HD;
    const short* Vb = Vt + (size_t)kvh * HD * S_LEN;

    {  // stage first K tile
      const short* Kg = Kb + (size_t)(t0 * 64) * HD;
#pragma unroll
      for (int i = 0; i < 4; ++i) {
        int c = tt + i * 256, row = c >> 4, jj = (c & 15) ^ (row & 7);
        gl_lds16(Kg + (size_t)row * HD + jj * 8, lK + c * 8);
      }
    }
    bf16x8 qf[2][4];
#pragma unroll
    for (int qa = 0; qa < 2; ++qa) {
      const short* qrow = Q + ((size_t)h * S_LEN + qt * 32 + qa * 16 + l15) * HD + l4 * 8;
#pragma unroll
      for (int fd = 0; fd < 4; ++fd)
        qf[qa][fd] = *reinterpret_cast<const bf16x8*>(qrow + fd * 32);
    }
    __syncthreads();

    int cur = 0;
    for (int kt = t0; kt < t1; ++kt) {
      const int c0 = kt * 64;
      if (kt + 1 < t1) {
        const short* Kg = Kb + (size_t)(c0 + 64) * HD;
        short* dst = lK + (cur ^ 1) * (64 * 128);
#pragma unroll
        for (int i = 0; i < 4; ++i) {
          int c = tt + i * 256, row = c >> 4, jj = (c & 15) ^ (row & 7);
          gl_lds16(Kg + (size_t)row * HD + jj * 8, dst + c * 8);
        }
      }
      const short* src = lK + cur * (64 * 128);
      f32x4 sf[2][4] = {};
      __builtin_amdgcn_s_setprio(1);
#pragma unroll
      for (int n = 0; n < 4; ++n) {
        bf16x8 kf[4];
#pragma unroll
        for (int fd = 0; fd < 4; ++fd) {
          int row = n * 16 + l15, jp = (l4 + fd * 4) ^ (l15 & 7);
          kf[fd] = *reinterpret_cast<const bf16x8*>(src + row * 128 + jp * 8);
        }
#pragma unroll
        for (int fd = 0; fd < 4; ++fd) {
          sf[0][n] = __builtin_amdgcn_mfma_f32_16x16x32_bf16(kf[fd], qf[0][fd], sf[0][n], 0, 0, 0);
          sf[1][n] = __builtin_amdgcn_mfma_f32_16x16x32_bf16(kf[fd], qf[1][fd], sf[1][n], 0, 0, 0);
        }
      }
      __builtin_amdgcn_s_setprio(0);
      bf16x8 vreg[8][2];
#pragma unroll
      for (int fd = 0; fd < 8; ++fd) {
        const short* vrow = Vb + (size_t)(fd * 16 + l15) * S_LEN + c0 + l4 * 8;
        vreg[fd][0] = *reinterpret_cast<const bf16x8*>(vrow);
        vreg[fd][1] = *reinterpret_cast<const bf16x8*>(vrow + 32);
      }
      const bool lastt = (kt == nkt - 1);
#pragma unroll
      for (int qa = 0; qa < 2; ++qa) {
        if (lastt) {  // wave-uniform: only the diagonal tile pays for masking
          const int qrow_g = qt * 32 + qa * 16 + l15;
#pragma unroll
          for (int n = 0; n < 4; ++n)
#pragma unroll
            for (int r = 0; r < 4; ++r)
              if ((c0 + n * 16 + l4 * 4 + r) > qrow_g) sf[qa][n][r] = -1e30f;
        }
        float mx = sf[qa][0][0];
#pragma unroll
        for (int n = 0; n < 4; ++n)
#pragma unroll
          for (int r = 0; r < 4; ++r) mx = fmaxf(mx, sf[qa][n][r]);
        mx = fmaxf(mx, __shfl_xor(mx, 16, 64));
        mx = fmaxf(mx, __shfl_xor(mx, 32, 64));
        // defer-max (T13): skip alpha shuffles + O-rescale when max stable.
        float mnew;
        if (__all(mx <= m_run[qa] + 8.f)) {
          mnew = m_run[qa];
        } else {
          mnew = fmaxf(m_run[qa], mx);
          float alpha = exp2f(m_run[qa] - mnew);
          m_run[qa] = mnew;
          lsum[qa] *= alpha;
          float aO[4];
#pragma unroll
          for (int r = 0; r < 4; ++r) aO[r] = __shfl(alpha, l4 * 4 + r, 64);
#pragma unroll
          for (int fd = 0; fd < 8; ++fd) {
            o[qa][fd][0] *= aO[0]; o[qa][fd][1] *= aO[1];
            o[qa][fd][2] *= aO[2]; o[qa][fd][3] *= aO[3];
          }
        }
        float ps = 0.f;
#pragma unroll
        for (int n = 0; n < 4; ++n)
#pragma unroll
          for (int r = 0; r < 4; ++r) {
            float e = exp2f(sf[qa][n][r] - mnew);
            sf[qa][n][r] = e;
            ps += e;
          }
        lsum[qa] += ps;
#pragma unroll
        for (int n = 0; n < 4; ++n)
#pragma unroll
          for (int rp = 0; rp < 2; ++rp) {
            unsigned int pkv =
                ((unsigned int)(unsigned short)f2bf(sf[qa][n][rp * 2 + 1]) << 16) |
                (unsigned short)f2bf(sf[qa][n][rp * 2]);
            int kv5 = ((n & 1) << 4) + l4 * 4 + rp * 2;
            lPu[w * 1024 + qa * 512 + ((n >> 1) << 8) +
                (l15 + ((kv5 >> 3) << 4)) * 4 + ((kv5 & 7) >> 1)] = pkv;
          }
      }
      asm volatile("s_waitcnt lgkmcnt(0)" ::: "memory");
      bf16x8 pf[2][2];
#pragma unroll
      for (int qa = 0; qa < 2; ++qa)
#pragma unroll
        for (int p = 0; p < 2; ++p)
          pf[qa][p] = *reinterpret_cast<const bf16x8*>(
              (const short*)lPu + (w * 1024 + qa * 512 + p * 256 + lane * 4) * 2);
      __builtin_amdgcn_s_setprio(1);
#pragma unroll
      for (int fd = 0; fd < 8; ++fd) {
        o[0][fd] = __builtin_amdgcn_mfma_f32_16x16x32_bf16(pf[0][0], vreg[fd][0], o[0][fd], 0, 0, 0);
        o[0][fd] = __builtin_amdgcn_mfma_f32_16x16x32_bf16(pf[0][1], vreg[fd][1], o[0][fd], 0, 0, 0);
        o[1][fd] = __builtin_amdgcn_mfma_f32_16x16x32_bf16(pf[1][0], vreg[fd][0], o[1][fd], 0, 0, 0);
        o[1][fd] = __builtin_amdgcn_mfma_f32_16x16x32_bf16(pf[1][1], vreg[fd][1], o[1][fd], 0, 0, 0);
      }
      __builtin_amdgcn_s_setprio(0);
      __syncthreads();
      cur ^= 1;
    }
  }
  // epilogue: reduce lsum, write stats + unnormalized partial O
#pragma unroll
  for (int qa = 0; qa < 2; ++qa) {
    float s = lsum[qa];
    s += __shfl_xor(s, 16, 64);
    s += __shfl_xor(s, 32, 64);
    if (l4 == 0)
      sout[(size_t)h * S_LEN + qt * 32 + qa * 16 + l15] = make_float2(m_run[qa], s);
#pragma unroll
    for (int fd = 0; fd < 8; ++fd)
#pragma unroll
      for (int r = 0; r < 4; ++r)
        pout[((size_t)h * S_LEN + qt * 32 + qa * 16 + l4 * 4 + r) * HD + fd * 16 + l15] =
            f2bf(o[qa][fd][r]);
  }
}

// merge the two kv-split partials -> AO, plus the w_proj fp32->bf16 pass
__global__ __launch_bounds__(256) void combine2_kernel(const short* __restrict__ p0,
                                                       const short* __restrict__ p1,
                                                       const float2* __restrict__ st0,
                                                       const float2* __restrict__ st1,
                                                       short* __restrict__ AO,
                                                       const float* __restrict__ wpf,
                                                       short* __restrict__ wpb) {
  {
    size_t base = (size_t)blockIdx.x * 4096 + threadIdx.x * 4;
#pragma unroll
    for (int it = 0; it < 4; ++it) {
      const float4 v = *reinterpret_cast<const float4*>(wpf + base + it * 1024);
      short4 oo;
      oo.x = f2bf(v.x); oo.y = f2bf(v.y); oo.z = f2bf(v.z); oo.w = f2bf(v.w);
      *reinterpret_cast<short4*>(wpb + base + it * 1024) = oo;
    }
  }
  int idx = (blockIdx.x * 256 + threadIdx.x) * 8;  // over NH*S*HD
  int h = idx >> 18;                 // S*HD = 2^18
  int rem = idx & ((1 << 18) - 1);
  int s = rem >> 7, d = rem & 127;
  float2 a = st0[(size_t)h * S_LEN + s];
  float2 b = st1[(size_t)h * S_LEN + s];
  float M = fmaxf(a.x, b.x);
  float w0 = exp2f(a.x - M), w1 = exp2f(b.x - M);
  float inv = 1.f / (a.y * w0 + b.y * w1);
  w0 *= inv; w1 *= inv;
  bf16x8 v0 = *reinterpret_cast<const bf16x8*>(p0 + idx);
  bf16x8 v1 = *reinterpret_cast<const bf16x8*>(p1 + idx);
  bf16x8 ov;
#pragma unroll
  for (int j = 0; j < 8; ++j)
    ov[j] = f2bf(bf2f(v0[j]) * w0 + bf2f(v1[j]) * w1);
  *reinterpret_cast<bf16x8*>(AO + (size_t)s * HDIM + h * HD + d) = ov;
}

extern "C" void kernel_launch(void* const* d_in, const int* in_sizes, int n_in,
                              void* d_out, int out_size, void* d_ws, size_t ws_size,
                              hipStream_t stream) {
  const float* hidden = (const float*)d_in[0];
  const float* w_attn = (const float*)d_in[1];
  const float* w_proj = (const float*)d_in[2];
  const float* rcos = (const float*)d_in[3];
  const float* rsin = (const float*)d_in[4];
  float* out = (float*)d_out;
  char* ws = (char*)d_ws;

  // workspace layout (overlaid, 112 MiB):
  //  [0,16Mi)    Xb (bf16 X)  -> dead after gemm1 -> AO (combine output)
  //  [16,64Mi)   Wab (bf16 w_attn) -> after gemm1: Qb[16,32) Kb[32,36)
  //              Vtb[36,40) St0[40,40.5) St1[41,41.5) Pt0[44,60)
  //  [64,112Mi)  QKVf (fp32, live gemm1->midk) -> then Pt1[64,80) Wpb[80,112)
  short* Xb  = (short*)(ws);
  short* Wab = (short*)(ws + (16u << 20));
  short* Qb  = (short*)(ws + (16u << 20));
  short* Kb  = (short*)(ws + (32u << 20));
  short* Vtb = (short*)(ws + (36u << 20));
  float2* St0 = (float2*)(ws + (40u << 20));
  float2* St1 = (float2*)(ws + (41u << 20));
  short* Pt0 = (short*)(ws + (44u << 20));
  float* QKVf = (float*)(ws + (64u << 20));
  short* Pt1 = (short*)(ws + (64u << 20));   // written after QKVf is dead
  short* Wpb = (short*)(ws + (80u << 20));   // written (by combine2) after QKVf dead
  short* AO  = Xb;

  const int nX = S_LEN * HDIM;       // 8388608
  const int nWa = QKVD * HDIM;       // 25165824

  hipFuncSetAttribute(reinterpret_cast<const void*>(gemm8p<384>),
                      hipFuncAttributeMaxDynamicSharedMemorySize, 131072);
  hipFuncSetAttribute(reinterpret_cast<const void*>(gemm8p<256>),
                      hipFuncAttributeMaxDynamicSharedMemorySize, 98304);

  cvt2_kernel<<<(nX + nWa) / 1024, 256, 0, stream>>>(hidden, Xb, nX, w_attn, Wab, nWa);
  gemm8p<384><<<256, 512, 131072, stream>>>(Xb, Wab, QKVf, S_LEN, QKVD, HDIM);
  midk_kernel<<<20992, 256, 0, stream>>>(QKVf, rcos, rsin, Qb, Kb, Vtb);
  attn_kernel<<<dim3(NKVH, 64, 2), 256, 0, stream>>>(Qb, Kb, Vtb, Pt0, Pt1, St0, St1);
  combine2_kernel<<<(NHEAD * S_LEN * HD / 8) / 256, 256, 0, stream>>>(
      Pt0, Pt1, St0, St1, AO, w_proj, Wpb);
  gemm8p<256><<<256, 512, 98304, stream>>>(AO, Wpb, out, S_LEN, HDIM, HDIM);
}

// Round 24
// 317.510 us; speedup vs baseline: 1.0718x; 1.0219x over previous
//
#include <hip/hip_runtime.h>
#include <cstdint>
#include <cstddef>

typedef __attribute__((ext_vector_type(4))) float f32x4;
typedef __attribute__((ext_vector_type(8))) short bf16x8;

#define S_LEN 2048
#define HDIM 4096
#define QKVD 6144
#define NHEAD 32
#define NKVH 8
#define HD 128
// Q pre-scaled by ATT_SCALE * log2(e): softmax runs in exp2 domain
#define QPRE 0.12751744631123533f

// fp32 -> bf16 RNE (finite inputs only)
__device__ __forceinline__ short f2bf(float f) {
  unsigned int u = __float_as_uint(f);
  u += 0x7FFFu + ((u >> 16) & 1u);
  return (short)(u >> 16);
}
__device__ __forceinline__ float bf2f(short s) {
  return __uint_as_float((unsigned int)(unsigned short)s << 16);
}

// async global->LDS, 16B per lane. LDS dest = wave-uniform base + lane*16.
__device__ __forceinline__ void gl_lds16(const short* g, short* l) {
  __builtin_amdgcn_global_load_lds((const __attribute__((address_space(1))) void*)g,
                                   (__attribute__((address_space(3))) void*)l,
                                   16, 0, 0);
}

template<int N> __device__ __forceinline__ void vmw() {
  if constexpr (N == 0) asm volatile("s_waitcnt vmcnt(0)" ::: "memory");
  else if constexpr (N == 1) asm volatile("s_waitcnt vmcnt(1)" ::: "memory");
  else if constexpr (N == 2) asm volatile("s_waitcnt vmcnt(2)" ::: "memory");
  else if constexpr (N == 3) asm volatile("s_waitcnt vmcnt(3)" ::: "memory");
  else if constexpr (N == 4) asm volatile("s_waitcnt vmcnt(4)" ::: "memory");
  // N==99: no wait
}

// fused fp32->bf16 conversion over up to two buffers (one launch)
__global__ void cvt2_kernel(const float* __restrict__ a, short* __restrict__ oa, int na,
                            const float* __restrict__ b, short* __restrict__ ob, int nb) {
  int i = (blockIdx.x * blockDim.x + threadIdx.x) * 4;
  const float* src; short* dst;
  if (i < na) { src = a + i; dst = oa + i; }
  else if (i < na + nb) { src = b + (i - na); dst = ob + (i - na); }
  else return;
  const float4 v = *reinterpret_cast<const float4*>(src);
  short4 o;
  o.x = f2bf(v.x); o.y = f2bf(v.y); o.z = f2bf(v.z); o.w = f2bf(v.w);
  *reinterpret_cast<short4*>(dst) = o;
}

// ---------------------------------------------------------------------------
// 4-phase snake GEMM with register-held frags (round-13/19/21/23 verified:
// ~97.5us, MfmaUtil ~45%, 0 bank conflicts). Gates (2, NQ+1, none, NQ+1) are
// the MINIMAL CORRECT ledger (round-20 refutation: each phase's gate protects
// the NEXT phase's reads). Round-14 lesson: keep 4 fine phases.
// Refuted directions ledger: 2-phase merge (r14), gate removal (r20),
// w_proj-in-attn (r15/17), occupancy-3 (r16), 3-way kv-split (r22).
// Geometry note: 256-sq tiles (m201 class) give only 192/128 blocks at
// M=2048 -> 25-50% CUs idle; 128-row tiles + full grid is this shape's
// optimum. 45% MfmaUtil is the geometry-constrained plateau.
// ---------------------------------------------------------------------------
#define PHASE(MH, NH, LOADA, LOADB, VM, STAGE) { \
    if (LOADA) { const short* bA = lA + buf * ATILE; \
      _Pragma("unroll") for (int m = 0; m < 2; ++m) { \
        int row = wm * 64 + (MH) * 32 + m * 16 + l15; \
        _Pragma("unroll") for (int kk = 0; kk < 2; ++kk) { \
          int slot = ((kk << 2) + l4) ^ (row & 7); \
          afH[m][kk] = *reinterpret_cast<const bf16x8*>(bA + row * 64 + slot * 8); } } } \
    if (LOADB) { const short* bB = lB + buf * BTILE; \
      _Pragma("unroll") for (int n = 0; n < NQ; ++n) { \
        int row = wn * (BN >> 2) + n * 32 + (NH) * 16 + l15; \
        _Pragma("unroll") for (int kk = 0; kk < 2; ++kk) { \
          int slot = ((kk << 2) + l4) ^ (row & 7); \
          bfH[n][kk] = *reinterpret_cast<const bf16x8*>(bB + row * 64 + slot * 8); } } } \
    STAGE; \
    vmw<(VM)>(); \
    __builtin_amdgcn_s_barrier(); \
    __builtin_amdgcn_sched_barrier(0); \
    __builtin_amdgcn_s_setprio(1); \
    _Pragma("unroll") for (int m = 0; m < 2; ++m) \
      _Pragma("unroll") for (int n = 0; n < NQ; ++n) \
        _Pragma("unroll") for (int kk = 0; kk < 2; ++kk) \
          acc[(MH) * 2 + m][(NH) * NQ + n] = __builtin_amdgcn_mfma_f32_16x16x32_bf16( \
              afH[m][kk], bfH[n][kk], acc[(MH) * 2 + m][(NH) * NQ + n], 0, 0, 0); \
    __builtin_amdgcn_s_setprio(0); }

template<int BN>
__global__ __launch_bounds__(512, 2) void gemm8p(const short* __restrict__ A,
                                                 const short* __restrict__ B,
                                                 float* __restrict__ C,
                                                 int M, int N, int K) {
  extern __shared__ short sm[];
  constexpr int NQ = BN / 128;
  constexpr int ATILE = 128 * 64;
  constexpr int BTILE = BN * 64;
  const int tid = threadIdx.x;
  const int wv = tid >> 6, lane = tid & 63;
  const int wm = wv >> 2, wn = wv & 3;
  const int l15 = lane & 15, l4 = lane >> 4;
  const int nbn = N / BN;
  const int nwg = gridDim.x;
  const int bid = blockIdx.x;
  const int sbid = (bid & 7) * (nwg >> 3) + (bid >> 3);  // XCD-contiguous (nwg%8==0)
  const int tm = (sbid / nbn) * 128, tn = (sbid % nbn) * BN;
  short* lA = sm;
  short* lB = sm + 2 * ATILE;
  (void)M;

  f32x4 acc[4][2 * NQ] = {};
  bf16x8 afH[2][2], bfH[NQ][2];

  auto stageA = [&](int k0, int bufi, int sel) {
    short* dst = lA + bufi * ATILE;
    int rowIdx = tid >> 3;
    int row = (rowIdx >> 5) * 64 + sel * 32 + (rowIdx & 31);
    int slot = tid & 7;
    gl_lds16(A + (size_t)(tm + row) * K + k0 + ((slot ^ (row & 7)) << 3),
             dst + row * 64 + slot * 8);
  };
  auto stageB = [&](int k0, int bufi, int par) {
    short* dst = lB + bufi * BTILE;
#pragma unroll
    for (int j = 0; j < NQ; ++j) {
      int rowIdx = (tid >> 3) + j * 64;
      int row = (rowIdx >> 4) * 32 + par * 16 + (rowIdx & 15);
      int slot = tid & 7;
      gl_lds16(B + (size_t)(tn + row) * K + k0 + ((slot ^ (row & 7)) << 3),
               dst + row * 64 + slot * 8);
    }
  };

  // prologue: tile 0, issue order = consume order
  stageA(0, 0, 0);
  stageB(0, 0, 0);
  stageB(0, 0, 1);
  stageA(0, 0, 1);
  vmw<NQ + 1>();
  __builtin_amdgcn_s_barrier();
  __builtin_amdgcn_sched_barrier(0);

  const int KT = K >> 6;
  for (int t = 0; t < KT - 1; ++t) {
    const int buf = t & 1, nbuf = buf ^ 1, nk0 = (t + 1) << 6;
    PHASE(0, 0, 1, 1, 2,      stageA(nk0, nbuf, 0))
    PHASE(0, 1, 0, 1, NQ + 1, stageB(nk0, nbuf, 0))
    PHASE(1, 1, 1, 0, 99,     stageB(nk0, nbuf, 1))
    PHASE(1, 0, 0, 1, NQ + 1, stageA(nk0, nbuf, 1))
  }
  {  // tail tile: no staging; drain progressively
    const int buf = (KT - 1) & 1;
    PHASE(0, 0, 1, 1, 1,  (void)0)
    PHASE(0, 1, 0, 1, 0,  (void)0)
    PHASE(1, 1, 1, 0, 99, (void)0)
    PHASE(1, 0, 0, 1, 99, (void)0)
  }
#pragma unroll
  for (int mg = 0; mg < 4; ++mg)
#pragma unroll
    for (int NH = 0; NH < 2; ++NH)
#pragma unroll
      for (int n = 0; n < NQ; ++n)
#pragma unroll
        for (int r = 0; r < 4; ++r) {
          int row = tm + wm * 64 + mg * 16 + l4 * 4 + r;
          int col = tn + wn * (BN >> 2) + n * 32 + NH * 16 + l15;
          C[(size_t)row * N + col] = acc[mg][NH * NQ + n][r];
        }
}

// fused mid kernel v2: rope VECTORIZED x4 (blocks [0,5120)) + V-transpose
// (blocks [5120,5632)). rope: one thread per (s,g,part,dquad) handles 4
// consecutive d-pairs via float4 loads / short4 stores (G13: no scalar bf16
// paths). cos[d+64]==cos[d] (emb = concat(freqs,freqs)).
__global__ __launch_bounds__(256) void midk_kernel(const float* __restrict__ qkv,
                                                   const float* __restrict__ cb,
                                                   const float* __restrict__ sb,
                                                   short* __restrict__ Q,
                                                   short* __restrict__ Kx,
                                                   short* __restrict__ Vt) {
  __shared__ short tile[64][72];
  if (blockIdx.x < 5120) {
    int tid = blockIdx.x * 256 + threadIdx.x;  // [0, 1310720)
    int dq = tid & 15;                         // quad index: dh = dq*4..dq*4+3
    int t2 = tid >> 4;
    int part = t2 % 5;                         // 0..3 = q heads in group, 4 = k
    int t3 = t2 / 5;
    int g = t3 & 7;
    int s = t3 >> 3;
    const float* base = qkv + (size_t)s * QKVD + g * 768 + part * 128;
    const int dh = dq * 4;
    const float4 v1 = *reinterpret_cast<const float4*>(base + dh);
    const float4 v2 = *reinterpret_cast<const float4*>(base + dh + 64);
    const float4 c  = *reinterpret_cast<const float4*>(cb + s * HD + dh);
    const float4 sn = *reinterpret_cast<const float4*>(sb + s * HD + dh);
    float o1x = v1.x * c.x - v2.x * sn.x, o2x = v2.x * c.x + v1.x * sn.x;
    float o1y = v1.y * c.y - v2.y * sn.y, o2y = v2.y * c.y + v1.y * sn.y;
    float o1z = v1.z * c.z - v2.z * sn.z, o2z = v2.z * c.z + v1.z * sn.z;
    float o1w = v1.w * c.w - v2.w * sn.w, o2w = v2.w * c.w + v1.w * sn.w;
    short* dst;
    if (part < 4) {
      o1x *= QPRE; o1y *= QPRE; o1z *= QPRE; o1w *= QPRE;
      o2x *= QPRE; o2y *= QPRE; o2z *= QPRE; o2w *= QPRE;
      dst = Q + ((size_t)(g * 4 + part) * S_LEN + s) * HD;
    } else {
      dst = Kx + ((size_t)g * S_LEN + s) * HD;
    }
    short4 w1, w2;
    w1.x = f2bf(o1x); w1.y = f2bf(o1y); w1.z = f2bf(o1z); w1.w = f2bf(o1w);
    w2.x = f2bf(o2x); w2.y = f2bf(o2y); w2.z = f2bf(o2z); w2.w = f2bf(o2w);
    *reinterpret_cast<short4*>(dst + dh) = w1;
    *reinterpret_cast<short4*>(dst + dh + 64) = w2;
  } else {
    const int b = blockIdx.x - 5120;
    const int kvh = b >> 6;
    const int s0 = ((b & 63) >> 1) * 64, d0 = (b & 1) * 64;
    const int t = threadIdx.x;
#pragma unroll
    for (int i = 0; i < 4; ++i) {
      int c = t + i * 256;
      int sl = c >> 4, dl = (c & 15) * 4;
      const float4 v = *reinterpret_cast<const float4*>(
          qkv + (size_t)(s0 + sl) * QKVD + kvh * 768 + 640 + d0 + dl);
      tile[sl][dl] = f2bf(v.x); tile[sl][dl + 1] = f2bf(v.y);
      tile[sl][dl + 2] = f2bf(v.z); tile[sl][dl + 3] = f2bf(v.w);
    }
    __syncthreads();
    short* Vtb = Vt + (size_t)kvh * HD * S_LEN;
#pragma unroll
    for (int i = 0; i < 2; ++i) {
      int dl = i * 32 + (t >> 3), sl = (t & 7) * 8;
      bf16x8 o;
#pragma unroll
      for (int j = 0; j < 8; ++j) o[j] = tile[sl + j][dl];
      *reinterpret_cast<bf16x8*>(Vtb + (size_t)(d0 + dl) * S_LEN + s0 + sl) = o;
    }
  }
}

// flash attention v8: 2-way kv-split + defer-max, (256,2) (verified best;
// r22 refuted 3-way split: z-major dispatch serializes splits into
// generations, no makespan gain, 1.5x fixed costs).
__global__ __launch_bounds__(256, 2) void attn_kernel(const short* __restrict__ Q,
                                                      const short* __restrict__ Kx,
                                                      const short* __restrict__ Vt,
                                                      short* __restrict__ part0,
                                                      short* __restrict__ part1,
                                                      float2* __restrict__ stat0,
                                                      float2* __restrict__ stat1) {
  __shared__ short lK[2 * 64 * 128];
  __shared__ unsigned int lPu[4 * 2 * 512];
  const int tt = threadIdx.x;
  const int w = tt >> 6, lane = tt & 63;
  const int l15 = lane & 15, l4 = lane >> 4;
  const int kvh = blockIdx.x;
  const int qt = 63 - blockIdx.y;
  const int z = blockIdx.z;
  const int h = kvh * 4 + w;
  short* pout = z ? part1 : part0;
  float2* sout = z ? stat1 : stat0;

  const int nkt = (qt >> 1) + 1;
  const int ts = (nkt + 1) >> 1;
  const int t0 = z ? ts : 0;
  const int t1 = z ? nkt : ts;

  f32x4 o[2][8] = {};
  float m_run[2] = {-1e30f, -1e30f};
  float lsum[2] = {0.f, 0.f};

  if (t0 < t1) {
    const short* Kb = Kx + (size_t)kvh * S_LEN * HD;
    const short* Vb = Vt + (size_t)kvh * HD * S_LEN;

    {  // stage first K tile
      const short* Kg = Kb + (size_t)(t0 * 64) * HD;
#pragma unroll
      for (int i = 0; i < 4; ++i) {
        int c = tt + i * 256, row = c >> 4, jj = (c & 15) ^ (row & 7);
        gl_lds16(Kg + (size_t)row * HD + jj * 8, lK + c * 8);
      }
    }
    bf16x8 qf[2][4];
#pragma unroll
    for (int qa = 0; qa < 2; ++qa) {
      const short* qrow = Q + ((size_t)h * S_LEN + qt * 32 + qa * 16 + l15) * HD + l4 * 8;
#pragma unroll
      for (int fd = 0; fd < 4; ++fd)
        qf[qa][fd] = *reinterpret_cast<const bf16x8*>(qrow + fd * 32);
    }
    __syncthreads();

    int cur = 0;
    for (int kt = t0; kt < t1; ++kt) {
      const int c0 = kt * 64;
      if (kt + 1 < t1) {
        const short* Kg = Kb + (size_t)(c0 + 64) * HD;
        short* dst = lK + (cur ^ 1) * (64 * 128);
#pragma unroll
        for (int i = 0; i < 4; ++i) {
          int c = tt + i * 256, row = c >> 4, jj = (c & 15) ^ (row & 7);
          gl_lds16(Kg + (size_t)row * HD + jj * 8, dst + c * 8);
        }
      }
      const short* src = lK + cur * (64 * 128);
      f32x4 sf[2][4] = {};
      __builtin_amdgcn_s_setprio(1);
#pragma unroll
      for (int n = 0; n < 4; ++n) {
        bf16x8 kf[4];
#pragma unroll
        for (int fd = 0; fd < 4; ++fd) {
          int row = n * 16 + l15, jp = (l4 + fd * 4) ^ (l15 & 7);
          kf[fd] = *reinterpret_cast<const bf16x8*>(src + row * 128 + jp * 8);
        }
#pragma unroll
        for (int fd = 0; fd < 4; ++fd) {
          sf[0][n] = __builtin_amdgcn_mfma_f32_16x16x32_bf16(kf[fd], qf[0][fd], sf[0][n], 0, 0, 0);
          sf[1][n] = __builtin_amdgcn_mfma_f32_16x16x32_bf16(kf[fd], qf[1][fd], sf[1][n], 0, 0, 0);
        }
      }
      __builtin_amdgcn_s_setprio(0);
      bf16x8 vreg[8][2];
#pragma unroll
      for (int fd = 0; fd < 8; ++fd) {
        const short* vrow = Vb + (size_t)(fd * 16 + l15) * S_LEN + c0 + l4 * 8;
        vreg[fd][0] = *reinterpret_cast<const bf16x8*>(vrow);
        vreg[fd][1] = *reinterpret_cast<const bf16x8*>(vrow + 32);
      }
      const bool lastt = (kt == nkt - 1);
#pragma unroll
      for (int qa = 0; qa < 2; ++qa) {
        if (lastt) {  // wave-uniform: only the diagonal tile pays for masking
          const int qrow_g = qt * 32 + qa * 16 + l15;
#pragma unroll
          for (int n = 0; n < 4; ++n)
#pragma unroll
            for (int r = 0; r < 4; ++r)
              if ((c0 + n * 16 + l4 * 4 + r) > qrow_g) sf[qa][n][r] = -1e30f;
        }
        float mx = sf[qa][0][0];
#pragma unroll
        for (int n = 0; n < 4; ++n)
#pragma unroll
          for (int r = 0; r < 4; ++r) mx = fmaxf(mx, sf[qa][n][r]);
        mx = fmaxf(mx, __shfl_xor(mx, 16, 64));
        mx = fmaxf(mx, __shfl_xor(mx, 32, 64));
        // defer-max (T13): skip alpha shuffles + O-rescale when max stable.
        float mnew;
        if (__all(mx <= m_run[qa] + 8.f)) {
          mnew = m_run[qa];
        } else {
          mnew = fmaxf(m_run[qa], mx);
          float alpha = exp2f(m_run[qa] - mnew);
          m_run[qa] = mnew;
          lsum[qa] *= alpha;
          float aO[4];
#pragma unroll
          for (int r = 0; r < 4; ++r) aO[r] = __shfl(alpha, l4 * 4 + r, 64);
#pragma unroll
          for (int fd = 0; fd < 8; ++fd) {
            o[qa][fd][0] *= aO[0]; o[qa][fd][1] *= aO[1];
            o[qa][fd][2] *= aO[2]; o[qa][fd][3] *= aO[3];
          }
        }
        float ps = 0.f;
#pragma unroll
        for (int n = 0; n < 4; ++n)
#pragma unroll
          for (int r = 0; r < 4; ++r) {
            float e = exp2f(sf[qa][n][r] - mnew);
            sf[qa][n][r] = e;
            ps += e;
          }
        lsum[qa] += ps;
#pragma unroll
        for (int n = 0; n < 4; ++n)
#pragma unroll
          for (int rp = 0; rp < 2; ++rp) {
            unsigned int pkv =
                ((unsigned int)(unsigned short)f2bf(sf[qa][n][rp * 2 + 1]) << 16) |
                (unsigned short)f2bf(sf[qa][n][rp * 2]);
            int kv5 = ((n & 1) << 4) + l4 * 4 + rp * 2;
            lPu[w * 1024 + qa * 512 + ((n >> 1) << 8) +
                (l15 + ((kv5 >> 3) << 4)) * 4 + ((kv5 & 7) >> 1)] = pkv;
          }
      }
      asm volatile("s_waitcnt lgkmcnt(0)" ::: "memory");
      bf16x8 pf[2][2];
#pragma unroll
      for (int qa = 0; qa < 2; ++qa)
#pragma unroll
        for (int p = 0; p < 2; ++p)
          pf[qa][p] = *reinterpret_cast<const bf16x8*>(
              (const short*)lPu + (w * 1024 + qa * 512 + p * 256 + lane * 4) * 2);
      __builtin_amdgcn_s_setprio(1);
#pragma unroll
      for (int fd = 0; fd < 8; ++fd) {
        o[0][fd] = __builtin_amdgcn_mfma_f32_16x16x32_bf16(pf[0][0], vreg[fd][0], o[0][fd], 0, 0, 0);
        o[0][fd] = __builtin_amdgcn_mfma_f32_16x16x32_bf16(pf[0][1], vreg[fd][1], o[0][fd], 0, 0, 0);
        o[1][fd] = __builtin_amdgcn_mfma_f32_16x16x32_bf16(pf[1][0], vreg[fd][0], o[1][fd], 0, 0, 0);
        o[1][fd] = __builtin_amdgcn_mfma_f32_16x16x32_bf16(pf[1][1], vreg[fd][1], o[1][fd], 0, 0, 0);
      }
      __builtin_amdgcn_s_setprio(0);
      __syncthreads();
      cur ^= 1;
    }
  }
  // epilogue: reduce lsum, write stats + unnormalized partial O
#pragma unroll
  for (int qa = 0; qa < 2; ++qa) {
    float s = lsum[qa];
    s += __shfl_xor(s, 16, 64);
    s += __shfl_xor(s, 32, 64);
    if (l4 == 0)
      sout[(size_t)h * S_LEN + qt * 32 + qa * 16 + l15] = make_float2(m_run[qa], s);
#pragma unroll
    for (int fd = 0; fd < 8; ++fd)
#pragma unroll
      for (int r = 0; r < 4; ++r)
        pout[((size_t)h * S_LEN + qt * 32 + qa * 16 + l4 * 4 + r) * HD + fd * 16 + l15] =
            f2bf(o[qa][fd][r]);
  }
}

// merge the two kv-split partials -> AO, plus the w_proj fp32->bf16 pass
__global__ __launch_bounds__(256) void combine2_kernel(const short* __restrict__ p0,
                                                       const short* __restrict__ p1,
                                                       const float2* __restrict__ st0,
                                                       const float2* __restrict__ st1,
                                                       short* __restrict__ AO,
                                                       const float* __restrict__ wpf,
                                                       short* __restrict__ wpb) {
  {
    size_t base = (size_t)blockIdx.x * 4096 + threadIdx.x * 4;
#pragma unroll
    for (int it = 0; it < 4; ++it) {
      const float4 v = *reinterpret_cast<const float4*>(wpf + base + it * 1024);
      short4 oo;
      oo.x = f2bf(v.x); oo.y = f2bf(v.y); oo.z = f2bf(v.z); oo.w = f2bf(v.w);
      *reinterpret_cast<short4*>(wpb + base + it * 1024) = oo;
    }
  }
  int idx = (blockIdx.x * 256 + threadIdx.x) * 8;  // over NH*S*HD
  int h = idx >> 18;                 // S*HD = 2^18
  int rem = idx & ((1 << 18) - 1);
  int s = rem >> 7, d = rem & 127;
  float2 a = st0[(size_t)h * S_LEN + s];
  float2 b = st1[(size_t)h * S_LEN + s];
  float M = fmaxf(a.x, b.x);
  float w0 = exp2f(a.x - M), w1 = exp2f(b.x - M);
  float inv = 1.f / (a.y * w0 + b.y * w1);
  w0 *= inv; w1 *= inv;
  bf16x8 v0 = *reinterpret_cast<const bf16x8*>(p0 + idx);
  bf16x8 v1 = *reinterpret_cast<const bf16x8*>(p1 + idx);
  bf16x8 ov;
#pragma unroll
  for (int j = 0; j < 8; ++j)
    ov[j] = f2bf(bf2f(v0[j]) * w0 + bf2f(v1[j]) * w1);
  *reinterpret_cast<bf16x8*>(AO + (size_t)s * HDIM + h * HD + d) = ov;
}

extern "C" void kernel_launch(void* const* d_in, const int* in_sizes, int n_in,
                              void* d_out, int out_size, void* d_ws, size_t ws_size,
                              hipStream_t stream) {
  const float* hidden = (const float*)d_in[0];
  const float* w_attn = (const float*)d_in[1];
  const float* w_proj = (const float*)d_in[2];
  const float* rcos = (const float*)d_in[3];
  const float* rsin = (const float*)d_in[4];
  float* out = (float*)d_out;
  char* ws = (char*)d_ws;

  // workspace layout (overlaid, 112 MiB):
  //  [0,16Mi)    Xb (bf16 X)  -> dead after gemm1 -> AO (combine output)
  //  [16,64Mi)   Wab (bf16 w_attn) -> after gemm1: Qb[16,32) Kb[32,36)
  //              Vtb[36,40) St0[40,40.5) St1[41,41.5) Pt0[44,60)
  //  [64,112Mi)  QKVf (fp32, live gemm1->midk) -> then Pt1[64,80) Wpb[80,112)
  short* Xb  = (short*)(ws);
  short* Wab = (short*)(ws + (16u << 20));
  short* Qb  = (short*)(ws + (16u << 20));
  short* Kb  = (short*)(ws + (32u << 20));
  short* Vtb = (short*)(ws + (36u << 20));
  float2* St0 = (float2*)(ws + (40u << 20));
  float2* St1 = (float2*)(ws + (41u << 20));
  short* Pt0 = (short*)(ws + (44u << 20));
  float* QKVf = (float*)(ws + (64u << 20));
  short* Pt1 = (short*)(ws + (64u << 20));   // written after QKVf is dead
  short* Wpb = (short*)(ws + (80u << 20));   // written (by combine2) after QKVf dead
  short* AO  = Xb;

  const int nX = S_LEN * HDIM;       // 8388608
  const int nWa = QKVD * HDIM;       // 25165824

  hipFuncSetAttribute(reinterpret_cast<const void*>(gemm8p<384>),
                      hipFuncAttributeMaxDynamicSharedMemorySize, 131072);
  hipFuncSetAttribute(reinterpret_cast<const void*>(gemm8p<256>),
                      hipFuncAttributeMaxDynamicSharedMemorySize, 98304);

  cvt2_kernel<<<(nX + nWa) / 1024, 256, 0, stream>>>(hidden, Xb, nX, w_attn, Wab, nWa);
  gemm8p<384><<<256, 512, 131072, stream>>>(Xb, Wab, QKVf, S_LEN, QKVD, HDIM);
  midk_kernel<<<5632, 256, 0, stream>>>(QKVf, rcos, rsin, Qb, Kb, Vtb);
  attn_kernel<<<dim3(NKVH, 64, 2), 256, 0, stream>>>(Qb, Kb, Vtb, Pt0, Pt1, St0, St1);
  combine2_kernel<<<(NHEAD * S_LEN * HD / 8) / 256, 256, 0, stream>>>(
      Pt0, Pt1, St0, St1, AO, w_proj, Wpb);
  gemm8p<256><<<256, 512, 98304, stream>>>(AO, Wpb, out, S_LEN, HDIM, HDIM);
}